// Round 15
// baseline (526.126 us; speedup 1.0000x reference)
//
#include <hip/hip_runtime.h>
#include <hip/hip_bf16.h>
#include <stdint.h>

#define NOUT 11008
#define KIN  4096
#define MTOK 4096
#define PLD  5504            // int32 elements per k-row of pw
#define NSTEP 64             // K-tiles of 64
#define NTN 43               // 11008 / 256
#define NTM 16               // 4096 / 256
#define ACH 32768            // 256 rows x 64k x 2B
#define BCH 32768            // 256 cols x 64k x 2B
#define WSA_BYTES ((size_t)NTM * NSTEP * ACH)   // 32 MB
#define WSW_BYTES ((size_t)NTN * NSTEP * BCH)   // 90.2 MB

typedef short bf16x8 __attribute__((ext_vector_type(8)));
typedef float f32x4  __attribute__((ext_vector_type(4)));

typedef __attribute__((address_space(3))) uint8_t lds_u8_t;
typedef __attribute__((address_space(1))) const uint8_t glb_u8_t;

__device__ __forceinline__ uint32_t bfpack(float lo, float hi){
    __hip_bfloat16 a = __float2bfloat16(lo);
    __hip_bfloat16 b = __float2bfloat16(hi);
    uint16_t ua, ub;
    __builtin_memcpy(&ua, &a, 2);
    __builtin_memcpy(&ub, &b, 2);
    return (uint32_t)ua | ((uint32_t)ub << 16);
}

__device__ __forceinline__ int swzA(int r){ return ((r >> 1) & 3) << 4; }

// ---------------- pre-pass A: x fp32 -> bf16, [mt][t64][m][128B: 2 k-halves, swz] ----------------
__global__ __launch_bounds__(256)
void prepA(const float* __restrict__ x, uint8_t* __restrict__ wsA)
{
    int gid = blockIdx.x * 256 + threadIdx.x;
    int m  = gid >> 10;
    int k  = (gid & 1023) << 2;
    float4 v = *reinterpret_cast<const float4*>(x + (size_t)m * KIN + k);
    uint32_t lo = bfpack(v.x, v.y), hi = bfpack(v.z, v.w);
    int mt = m >> 8, ml = m & 255, t = k >> 6, kh = (k >> 5) & 1, kl = k & 31;
    size_t dst = (size_t)(mt * NSTEP + t) * ACH + ml * 128 + kh * 64 + ((kl * 2) ^ swzA(ml));
    *reinterpret_cast<uint2*>(wsA + dst) = make_uint2(lo, hi);
}

// ---------------- pre-pass W: dequant int4 -> bf16 chunks [nt][t64][col][128B swz] ----------------
__global__ __launch_bounds__(256)
void prepW2(const int32_t* __restrict__ pw, const float* __restrict__ sc,
            uint8_t* __restrict__ wsW)
{
    const int t  = blockIdx.x;                 // 0..63 (K-tile of 64)
    const int nt = blockIdx.y;                 // 0..42
    const int c  = threadIdx.x;
    const int col = nt * 256 + c;
    const int np  = col >> 1;
    const uint32_t sh = (uint32_t)(col & 1) * 4;
    const int32_t* p = pw + (size_t)(t * 64) * PLD + np;
    const float s  = sc[(size_t)(t >> 1) * NOUT + col];   // scale block = 128 k = 2 tiles
    const float m8 = -8.f * s;
    uint8_t* out = wsW + ((size_t)nt * NSTEP + t) * BCH + c * 128;
#pragma unroll
    for (int k8 = 0; k8 < 8; ++k8) {           // 8 k-octets over 64 k
        uint32_t r[4];
#pragma unroll
        for (int kk = 0; kk < 4; ++kk) {
            uint32_t w0 = (uint32_t)p[(size_t)(k8 * 8 + kk * 2)     * PLD];
            uint32_t w1 = (uint32_t)p[(size_t)(k8 * 8 + kk * 2 + 1) * PLD];
            float f0 = fmaf((float)((w0 >> sh) & 15u), s, m8);
            float f1 = fmaf((float)((w1 >> sh) & 15u), s, m8);
            r[kk] = bfpack(f0, f1);
        }
        *reinterpret_cast<uint4*>(out + (k8 >> 2) * 64 + (((k8 & 3) * 16) ^ swzA(c)))
            = *reinterpret_cast<uint4*>(r);
    }
}

// ---------------- main GEMM: 256x256, 8 waves, BK=64 pairs (half barrier rate), A 3-buf + B 2-buf ----------------
__global__ __launch_bounds__(512, 1)
void qlin_gemm15(const uint8_t* __restrict__ wsA, const uint8_t* __restrict__ wsW,
                 const float* __restrict__ bias, float* __restrict__ y)
{
    __shared__ __align__(16) uint8_t ldsA[3][ACH];   // 96 KB
    __shared__ __align__(16) uint8_t ldsB[2][BCH];   // 64 KB  -> 160 KB total

    const int tid  = threadIdx.x;
    const int lane = tid & 63;
    const int wid  = tid >> 6;
    const int wr = wid >> 2, wc = wid & 3;   // 2x4 wave grid, 128x64 per wave

    const int lb = (blockIdx.x & 7) * 86 + (blockIdx.x >> 3);  // bijective XCD swizzle (688 = 8*86)
    const int mt = lb / NTN, nt = lb % NTN;
    const int m0 = mt * 256, n0 = nt * 256;

    const int cl = lane & 15;
    const int k8 = lane >> 4;

    int aOff[8];                               // k-half h adds +64
#pragma unroll
    for (int i = 0; i < 8; ++i) {
        int ml = wr * 128 + i * 16 + cl;
        aOff[i] = ml * 128 + ((k8 * 16) ^ swzA(ml));
    }
    int bOff[4];
#pragma unroll
    for (int j = 0; j < 4; ++j) {
        int cc = wc * 64 + j * 16 + cl;
        bOff[j] = cc * 128 + ((k8 * 16) ^ swzA(cc));
    }

    const uint8_t* wsAbase = wsA + (size_t)mt * NSTEP * ACH;
    const uint8_t* wsWbase = wsW + (size_t)nt * NSTEP * BCH;

    f32x4 acc[8][4];
#pragma unroll
    for (int i = 0; i < 8; ++i)
#pragma unroll
        for (int j = 0; j < 4; ++j)
            acc[i][j] = (f32x4){0.f, 0.f, 0.f, 0.f};

    bf16x8 af[4], bf2[4][2];   // bf2 held across the pair (static indices only)

#define STAGE_A(buf, t) do { \
    const uint8_t* g_ = wsAbase + (size_t)(t) * ACH + tid * 16; \
    __builtin_amdgcn_global_load_lds((glb_u8_t*)(g_),         (lds_u8_t*)(&ldsA[buf][tid*16]),         16, 0, 0); \
    __builtin_amdgcn_global_load_lds((glb_u8_t*)(g_ + 8192),  (lds_u8_t*)(&ldsA[buf][tid*16 + 8192]),  16, 0, 0); \
    __builtin_amdgcn_global_load_lds((glb_u8_t*)(g_ + 16384), (lds_u8_t*)(&ldsA[buf][tid*16 + 16384]), 16, 0, 0); \
    __builtin_amdgcn_global_load_lds((glb_u8_t*)(g_ + 24576), (lds_u8_t*)(&ldsA[buf][tid*16 + 24576]), 16, 0, 0); \
} while(0)

#define STAGE_B(buf, t) do { \
    const uint8_t* g_ = wsWbase + (size_t)(t) * BCH + tid * 16; \
    __builtin_amdgcn_global_load_lds((glb_u8_t*)(g_),         (lds_u8_t*)(&ldsB[buf][tid*16]),         16, 0, 0); \
    __builtin_amdgcn_global_load_lds((glb_u8_t*)(g_ + 8192),  (lds_u8_t*)(&ldsB[buf][tid*16 + 8192]),  16, 0, 0); \
    __builtin_amdgcn_global_load_lds((glb_u8_t*)(g_ + 16384), (lds_u8_t*)(&ldsB[buf][tid*16 + 16384]), 16, 0, 0); \
    __builtin_amdgcn_global_load_lds((glb_u8_t*)(g_ + 24576), (lds_u8_t*)(&ldsB[buf][tid*16 + 24576]), 16, 0, 0); \
} while(0)

#define BAR() do { \
    asm volatile("" ::: "memory"); \
    __builtin_amdgcn_s_barrier(); \
    asm volatile("" ::: "memory"); \
} while(0)

#define MFMA16(IBASE, H) do { \
    __builtin_amdgcn_s_setprio(1); \
    _Pragma("unroll") \
    for (int j = 0; j < 4; ++j) { _Pragma("unroll") \
        for (int i = 0; i < 4; ++i) \
            acc[(IBASE) + i][j] = __builtin_amdgcn_mfma_f32_16x16x32_bf16(af[i], bf2[j][H], acc[(IBASE) + i][j], 0, 0, 0); } \
    __builtin_amdgcn_s_setprio(0); \
} while(0)

    // odd phase (pair t): stage B(t+1); read B h0+h1 (held) + A m-half0; MFMA m-half0 over K=64
#define PH_O(cbA, cbB, sbB, tB) do { \
    STAGE_B(sbB, tB); \
    _Pragma("unroll") \
    for (int j = 0; j < 4; ++j) bf2[j][0] = *reinterpret_cast<const bf16x8*>(ldsB[cbB] + bOff[j]); \
    _Pragma("unroll") \
    for (int i = 0; i < 4; ++i) af[i] = *reinterpret_cast<const bf16x8*>(ldsA[cbA] + aOff[i]); \
    BAR(); \
    MFMA16(0, 0); \
    _Pragma("unroll") \
    for (int j = 0; j < 4; ++j) bf2[j][1] = *reinterpret_cast<const bf16x8*>(ldsB[cbB] + bOff[j] + 64); \
    _Pragma("unroll") \
    for (int i = 0; i < 4; ++i) af[i] = *reinterpret_cast<const bf16x8*>(ldsA[cbA] + aOff[i] + 64); \
    MFMA16(0, 1); \
    BAR(); \
} while(0)

    // even phase: stage A(t+2); read A m-half1; MFMA m-half1 (bf2 held); counted vmcnt(4)
#define PH_E(cbA, sbA, tA) do { \
    STAGE_A(sbA, tA); \
    _Pragma("unroll") \
    for (int i = 0; i < 4; ++i) af[i] = *reinterpret_cast<const bf16x8*>(ldsA[cbA] + aOff[4 + i]); \
    BAR(); \
    MFMA16(4, 0); \
    _Pragma("unroll") \
    for (int i = 0; i < 4; ++i) af[i] = *reinterpret_cast<const bf16x8*>(ldsA[cbA] + aOff[4 + i] + 64); \
    MFMA16(4, 1); \
    asm volatile("s_waitcnt vmcnt(4)" ::: "memory"); \
    __builtin_amdgcn_sched_barrier(0); \
    BAR(); \
} while(0)

    // ---- prologue: A0->s0, B0->s0, A1->s1 (12 glds); vmcnt(4) leaves only A1 in flight ----
    STAGE_A(0, 0);
    STAGE_B(0, 0);
    STAGE_A(1, 1);
    asm volatile("s_waitcnt vmcnt(4)" ::: "memory");
    __builtin_amdgcn_sched_barrier(0);
    BAR();

    // ---- main loop: pairs t=0..59 (slot period 6), then 4 tail pairs with clamped staging ----
    // pair t: reads A slot t%3 / B slot t%2; stages B(t+1)->(t+1)%2, A(t+2)->(t+2)%3.
    // vmcnt(4) at pair end: in-flight = A(t+2) only; B(t+1) and A(t+1) provably drained (FIFO).
#pragma unroll 1
    for (int tb = 0; tb < 60; tb += 6) {
        PH_O(0, 0, 1, tb + 1);  PH_E(0, 2, tb + 2);
        PH_O(1, 1, 0, tb + 2);  PH_E(1, 0, tb + 3);
        PH_O(2, 0, 1, tb + 3);  PH_E(2, 1, tb + 4);
        PH_O(0, 1, 0, tb + 4);  PH_E(0, 2, tb + 5);
        PH_O(1, 0, 1, tb + 5);  PH_E(1, 0, tb + 6);
        PH_O(2, 1, 0, tb + 6);  PH_E(2, 1, tb + 7);
    }
    // tail: t=60..63 (clamped re-stages of tile 63 are dead writes, keep vmem count uniform)
    PH_O(0, 0, 1, 61);  PH_E(0, 2, 62);
    PH_O(1, 1, 0, 62);  PH_E(1, 0, 63);
    PH_O(2, 0, 1, 63);  PH_E(2, 1, 63);
    PH_O(0, 1, 0, 63);  PH_E(0, 2, 63);

    // ---- epilogue: acc + bias -> y (C/D: col=lane&15, row=(lane>>4)*4+reg) ----
    float bv[4];
#pragma unroll
    for (int j = 0; j < 4; ++j) bv[j] = bias[n0 + wc * 64 + j * 16 + cl];
    const int rg = (lane >> 4) * 4;
#pragma unroll
    for (int i = 0; i < 8; ++i) {
        const int mrow = m0 + wr * 128 + i * 16 + rg;
#pragma unroll
        for (int r = 0; r < 4; ++r) {
            float* yp = y + (size_t)(mrow + r) * NOUT + n0 + wc * 64 + cl;
#pragma unroll
            for (int j = 0; j < 4; ++j)
                yp[j * 16] = acc[i][j][r] + bv[j];
        }
    }

#undef STAGE_A
#undef STAGE_B
#undef BAR
#undef MFMA16
#undef PH_O
#undef PH_E
}

extern "C" void kernel_launch(void* const* d_in, const int* in_sizes, int n_in,
                              void* d_out, int out_size, void* d_ws, size_t ws_size,
                              hipStream_t stream)
{
    const float*   xin  = (const float*)d_in[0];
    const int32_t* pw   = (const int32_t*)d_in[1];   // harness pushes int8 as int32
    const float*   scal = (const float*)d_in[2];
    const float*   bias = (const float*)d_in[3];
    float* y = (float*)d_out;

    uint8_t* wsA = (uint8_t*)d_ws;
    uint8_t* wsW = wsA + WSA_BYTES;

    prepA<<<dim3((MTOK * (KIN / 4)) / 256), 256, 0, stream>>>(xin, wsA);
    prepW2<<<dim3(NSTEP, NTN), 256, 0, stream>>>(pw, scal, wsW);
    qlin_gemm15<<<dim3(NTM * NTN), 512, 0, stream>>>(wsA, wsW, bias, y);
}

// Round 16
// 522.404 us; speedup vs baseline: 1.0071x; 1.0071x over previous
//
#include <hip/hip_runtime.h>
#include <hip/hip_bf16.h>
#include <stdint.h>

#define NOUT 11008
#define KIN  4096
#define MTOK 4096
#define PLD  5504            // int32 elements per k-row of pw
#define NSTEP 64             // K-tiles of 64
#define NTN 43               // 11008 / 256
#define NTM 16               // 4096 / 256
#define ACH 32768            // 256 rows x 64k x 2B
#define BCH 32768            // 256 cols x 64k x 2B
#define WSA_BYTES ((size_t)NTM * NSTEP * ACH)   // 32 MB
#define WSW_BYTES ((size_t)NTN * NSTEP * BCH)   // 90.2 MB

typedef short bf16x8 __attribute__((ext_vector_type(8)));
typedef float f32x4  __attribute__((ext_vector_type(4)));

typedef __attribute__((address_space(3))) uint8_t lds_u8_t;
typedef __attribute__((address_space(1))) const uint8_t glb_u8_t;

__device__ __forceinline__ uint32_t bfpack(float lo, float hi){
    __hip_bfloat16 a = __float2bfloat16(lo);
    __hip_bfloat16 b = __float2bfloat16(hi);
    uint16_t ua, ub;
    __builtin_memcpy(&ua, &a, 2);
    __builtin_memcpy(&ub, &b, 2);
    return (uint32_t)ua | ((uint32_t)ub << 16);
}

// 128-B row swizzle: 8 x 16B slots, slot' = slot ^ (row & 7)  (G4 formula; 16 lanes -> 2-way = free)
__device__ __forceinline__ int slotswz(int slot, int row){ return ((slot ^ (row & 7)) << 4); }

// ---------------- pre-pass A: x fp32 -> bf16, [mt][t64][m][128B row, 8-slot swz] ----------------
__global__ __launch_bounds__(256)
void prepA(const float* __restrict__ x, uint8_t* __restrict__ wsA)
{
    int gid = blockIdx.x * 256 + threadIdx.x;
    int m  = gid >> 10;
    int k  = (gid & 1023) << 2;
    float4 v = *reinterpret_cast<const float4*>(x + (size_t)m * KIN + k);
    uint32_t lo = bfpack(v.x, v.y), hi = bfpack(v.z, v.w);
    int mt = m >> 8, ml = m & 255, t = k >> 6;
    int kb = (k & 63) * 2;                       // byte pos of this k-quad within the 128B row
    size_t dst = (size_t)(mt * NSTEP + t) * ACH + ml * 128
               + slotswz(kb >> 4, ml) + (kb & 15);
    *reinterpret_cast<uint2*>(wsA + dst) = make_uint2(lo, hi);
}

// ---------------- pre-pass W: dequant int4 -> bf16 chunks [nt][t64][col][128B row, 8-slot swz] ----------------
__global__ __launch_bounds__(256)
void prepW2(const int32_t* __restrict__ pw, const float* __restrict__ sc,
            uint8_t* __restrict__ wsW)
{
    const int t  = blockIdx.x;                 // 0..63 (K-tile of 64)
    const int nt = blockIdx.y;                 // 0..42
    const int c  = threadIdx.x;
    const int col = nt * 256 + c;
    const int np  = col >> 1;
    const uint32_t sh = (uint32_t)(col & 1) * 4;
    const int32_t* p = pw + (size_t)(t * 64) * PLD + np;
    const float s  = sc[(size_t)(t >> 1) * NOUT + col];   // scale block = 128 k = 2 tiles
    const float m8 = -8.f * s;
    uint8_t* out = wsW + ((size_t)nt * NSTEP + t) * BCH + c * 128;
#pragma unroll
    for (int k8 = 0; k8 < 8; ++k8) {           // 8 k-octets = 8 slots of 16B
        uint32_t r[4];
#pragma unroll
        for (int kk = 0; kk < 4; ++kk) {
            uint32_t w0 = (uint32_t)p[(size_t)(k8 * 8 + kk * 2)     * PLD];
            uint32_t w1 = (uint32_t)p[(size_t)(k8 * 8 + kk * 2 + 1) * PLD];
            float f0 = fmaf((float)((w0 >> sh) & 15u), s, m8);
            float f1 = fmaf((float)((w1 >> sh) & 15u), s, m8);
            r[kk] = bfpack(f0, f1);
        }
        *reinterpret_cast<uint4*>(out + slotswz(k8, c)) = *reinterpret_cast<uint4*>(r);
    }
}

// ---------------- main GEMM: r15 skeleton, corrected 8-slot swizzle ----------------
__global__ __launch_bounds__(512, 1)
void qlin_gemm16(const uint8_t* __restrict__ wsA, const uint8_t* __restrict__ wsW,
                 const float* __restrict__ bias, float* __restrict__ y)
{
    __shared__ __align__(16) uint8_t ldsA[3][ACH];   // 96 KB
    __shared__ __align__(16) uint8_t ldsB[2][BCH];   // 64 KB  -> 160 KB total

    const int tid  = threadIdx.x;
    const int lane = tid & 63;
    const int wid  = tid >> 6;
    const int wr = wid >> 2, wc = wid & 3;   // 2x4 wave grid, 128x64 per wave

    const int lb = (blockIdx.x & 7) * 86 + (blockIdx.x >> 3);  // bijective XCD swizzle (688 = 8*86)
    const int mt = lb / NTN, nt = lb % NTN;
    const int m0 = mt * 256, n0 = nt * 256;

    const int cl = lane & 15;
    const int k8 = lane >> 4;                // slot 0..3 (h=0); h=1 -> slot k8+4 == ^64 after swz

    int aOff[8];
#pragma unroll
    for (int i = 0; i < 8; ++i) {
        int ml = wr * 128 + i * 16 + cl;
        aOff[i] = ml * 128 + slotswz(k8, ml);
    }
    int bOff[4];
#pragma unroll
    for (int j = 0; j < 4; ++j) {
        int cc = wc * 64 + j * 16 + cl;
        bOff[j] = cc * 128 + slotswz(k8, cc);
    }

    const uint8_t* wsAbase = wsA + (size_t)mt * NSTEP * ACH;
    const uint8_t* wsWbase = wsW + (size_t)nt * NSTEP * BCH;

    f32x4 acc[8][4];
#pragma unroll
    for (int i = 0; i < 8; ++i)
#pragma unroll
        for (int j = 0; j < 4; ++j)
            acc[i][j] = (f32x4){0.f, 0.f, 0.f, 0.f};

    bf16x8 af[4], bf2[4][2];   // bf2 held across the pair (static indices only)

#define STAGE_A(buf, t) do { \
    const uint8_t* g_ = wsAbase + (size_t)(t) * ACH + tid * 16; \
    __builtin_amdgcn_global_load_lds((glb_u8_t*)(g_),         (lds_u8_t*)(&ldsA[buf][tid*16]),         16, 0, 0); \
    __builtin_amdgcn_global_load_lds((glb_u8_t*)(g_ + 8192),  (lds_u8_t*)(&ldsA[buf][tid*16 + 8192]),  16, 0, 0); \
    __builtin_amdgcn_global_load_lds((glb_u8_t*)(g_ + 16384), (lds_u8_t*)(&ldsA[buf][tid*16 + 16384]), 16, 0, 0); \
    __builtin_amdgcn_global_load_lds((glb_u8_t*)(g_ + 24576), (lds_u8_t*)(&ldsA[buf][tid*16 + 24576]), 16, 0, 0); \
} while(0)

#define STAGE_B(buf, t) do { \
    const uint8_t* g_ = wsWbase + (size_t)(t) * BCH + tid * 16; \
    __builtin_amdgcn_global_load_lds((glb_u8_t*)(g_),         (lds_u8_t*)(&ldsB[buf][tid*16]),         16, 0, 0); \
    __builtin_amdgcn_global_load_lds((glb_u8_t*)(g_ + 8192),  (lds_u8_t*)(&ldsB[buf][tid*16 + 8192]),  16, 0, 0); \
    __builtin_amdgcn_global_load_lds((glb_u8_t*)(g_ + 16384), (lds_u8_t*)(&ldsB[buf][tid*16 + 16384]), 16, 0, 0); \
    __builtin_amdgcn_global_load_lds((glb_u8_t*)(g_ + 24576), (lds_u8_t*)(&ldsB[buf][tid*16 + 24576]), 16, 0, 0); \
} while(0)

#define BAR() do { \
    asm volatile("" ::: "memory"); \
    __builtin_amdgcn_s_barrier(); \
    asm volatile("" ::: "memory"); \
} while(0)

#define MFMA16(IBASE, H) do { \
    __builtin_amdgcn_s_setprio(1); \
    _Pragma("unroll") \
    for (int j = 0; j < 4; ++j) { _Pragma("unroll") \
        for (int i = 0; i < 4; ++i) \
            acc[(IBASE) + i][j] = __builtin_amdgcn_mfma_f32_16x16x32_bf16(af[i], bf2[j][H], acc[(IBASE) + i][j], 0, 0, 0); } \
    __builtin_amdgcn_s_setprio(0); \
} while(0)

    // odd phase (pair t): stage B(t+1); read B h0+h1 (held) + A m-half0; MFMA m-half0 over K=64
#define PH_O(cbA, cbB, sbB, tB) do { \
    STAGE_B(sbB, tB); \
    _Pragma("unroll") \
    for (int j = 0; j < 4; ++j) bf2[j][0] = *reinterpret_cast<const bf16x8*>(ldsB[cbB] + bOff[j]); \
    _Pragma("unroll") \
    for (int i = 0; i < 4; ++i) af[i] = *reinterpret_cast<const bf16x8*>(ldsA[cbA] + aOff[i]); \
    BAR(); \
    MFMA16(0, 0); \
    _Pragma("unroll") \
    for (int j = 0; j < 4; ++j) bf2[j][1] = *reinterpret_cast<const bf16x8*>(ldsB[cbB] + (bOff[j] ^ 64)); \
    _Pragma("unroll") \
    for (int i = 0; i < 4; ++i) af[i] = *reinterpret_cast<const bf16x8*>(ldsA[cbA] + (aOff[i] ^ 64)); \
    MFMA16(0, 1); \
    BAR(); \
} while(0)

    // even phase: stage A(t+2); read A m-half1; MFMA m-half1 (bf2 held); counted vmcnt(4)
#define PH_E(cbA, sbA, tA) do { \
    STAGE_A(sbA, tA); \
    _Pragma("unroll") \
    for (int i = 0; i < 4; ++i) af[i] = *reinterpret_cast<const bf16x8*>(ldsA[cbA] + aOff[4 + i]); \
    BAR(); \
    MFMA16(4, 0); \
    _Pragma("unroll") \
    for (int i = 0; i < 4; ++i) af[i] = *reinterpret_cast<const bf16x8*>(ldsA[cbA] + (aOff[4 + i] ^ 64)); \
    MFMA16(4, 1); \
    asm volatile("s_waitcnt vmcnt(4)" ::: "memory"); \
    __builtin_amdgcn_sched_barrier(0); \
    BAR(); \
} while(0)

    // ---- prologue: A0->s0, B0->s0, A1->s1 (12 glds); vmcnt(4) leaves only A1 in flight ----
    STAGE_A(0, 0);
    STAGE_B(0, 0);
    STAGE_A(1, 1);
    asm volatile("s_waitcnt vmcnt(4)" ::: "memory");
    __builtin_amdgcn_sched_barrier(0);
    BAR();

    // ---- main loop: pairs t=0..59 (slot period 6), then 4 tail pairs with clamped staging ----
    // pair t: reads A slot t%3 / B slot t%2; stages B(t+1)->(t+1)%2, A(t+2)->(t+2)%3.
    // vmcnt(4) at pair end: in-flight = A(t+2) only; B(t+1) and A(t+1) provably drained (FIFO).
#pragma unroll 1
    for (int tb = 0; tb < 60; tb += 6) {
        PH_O(0, 0, 1, tb + 1);  PH_E(0, 2, tb + 2);
        PH_O(1, 1, 0, tb + 2);  PH_E(1, 0, tb + 3);
        PH_O(2, 0, 1, tb + 3);  PH_E(2, 1, tb + 4);
        PH_O(0, 1, 0, tb + 4);  PH_E(0, 2, tb + 5);
        PH_O(1, 0, 1, tb + 5);  PH_E(1, 0, tb + 6);
        PH_O(2, 1, 0, tb + 6);  PH_E(2, 1, tb + 7);
    }
    // tail: t=60..63 (clamped re-stages of tile 63 are dead writes, keep vmem count uniform)
    PH_O(0, 0, 1, 61);  PH_E(0, 2, 62);
    PH_O(1, 1, 0, 62);  PH_E(1, 0, 63);
    PH_O(2, 0, 1, 63);  PH_E(2, 1, 63);
    PH_O(0, 1, 0, 63);  PH_E(0, 2, 63);

    // ---- epilogue: acc + bias -> y (C/D: col=lane&15, row=(lane>>4)*4+reg) ----
    float bv[4];
#pragma unroll
    for (int j = 0; j < 4; ++j) bv[j] = bias[n0 + wc * 64 + j * 16 + cl];
    const int rg = (lane >> 4) * 4;
#pragma unroll
    for (int i = 0; i < 8; ++i) {
        const int mrow = m0 + wr * 128 + i * 16 + rg;
#pragma unroll
        for (int r = 0; r < 4; ++r) {
            float* yp = y + (size_t)(mrow + r) * NOUT + n0 + wc * 64 + cl;
#pragma unroll
            for (int j = 0; j < 4; ++j)
                yp[j * 16] = acc[i][j][r] + bv[j];
        }
    }

#undef STAGE_A
#undef STAGE_B
#undef BAR
#undef MFMA16
#undef PH_O
#undef PH_E
}

extern "C" void kernel_launch(void* const* d_in, const int* in_sizes, int n_in,
                              void* d_out, int out_size, void* d_ws, size_t ws_size,
                              hipStream_t stream)
{
    const float*   xin  = (const float*)d_in[0];
    const int32_t* pw   = (const int32_t*)d_in[1];   // harness pushes int8 as int32
    const float*   scal = (const float*)d_in[2];
    const float*   bias = (const float*)d_in[3];
    float* y = (float*)d_out;

    uint8_t* wsA = (uint8_t*)d_ws;
    uint8_t* wsW = wsA + WSA_BYTES;

    prepA<<<dim3((MTOK * (KIN / 4)) / 256), 256, 0, stream>>>(xin, wsA);
    prepW2<<<dim3(NSTEP, NTN), 256, 0, stream>>>(pw, scal, wsW);
    qlin_gemm16<<<dim3(NTM * NTN), 512, 0, stream>>>(wsA, wsW, bias, y);
}